// Round 2
// baseline (596.806 us; speedup 1.0000x reference)
//
#include <hip/hip_runtime.h>
#include <stdint.h>

// bf16 flash-attention forward, causal, B=2 H=16 T=4096 D=128, fp32 in/out.
// S^T = K*Q^T formulation (q lives on lane&31 for softmax), O^T = V^T*P^T
// (alpha rescale is per-lane). All MFMA operand LDS reads are ds_read_b128.

typedef __bf16 bf16x8 __attribute__((ext_vector_type(8)));
typedef float f32x16 __attribute__((ext_vector_type(16)));
typedef unsigned short u16x8 __attribute__((ext_vector_type(8)));
typedef unsigned short u16x4 __attribute__((ext_vector_type(4)));

#define T_SEQ 4096
#define D_HEAD 128
#define BQ 128          // q rows per block (4 waves x 32)
#define BK 64           // kv rows per tile
#define KSTR 136        // K_lds row stride in shorts (128 + 8 pad, 16B-aligned rows)
#define VSTR 72         // Vt_lds row stride in shorts (64 + 8 pad)
#define PSTR 72         // Pq row stride in shorts

__device__ __forceinline__ unsigned short f2bf(float x) {
    unsigned int u = __builtin_bit_cast(unsigned int, x);
    return (unsigned short)((u + 0x7fffu + ((u >> 16) & 1u)) >> 16);  // RNE
}

__global__ __launch_bounds__(256, 2) void fa_fwd(
    const float* __restrict__ Qg, const float* __restrict__ Kg,
    const float* __restrict__ Vg, float* __restrict__ Og)
{
    __shared__ unsigned short K_lds[BK * KSTR];        // K[kv][d]     17408 B
    __shared__ unsigned short Vt_lds[D_HEAD * VSTR];   // V^T[d][kv]   18432 B
    __shared__ unsigned short Pq_lds[4 * 32 * PSTR];   // per-wave P[q][kv] 18432 B

    const int tid  = threadIdx.x;
    const int w    = tid >> 6;      // wave 0..3
    const int lane = tid & 63;
    const int r    = lane & 31;     // n-index within MFMA tiles
    const int h    = lane >> 5;     // half-wave

    const int qt = (int)(gridDim.x - 1 - blockIdx.x); // big tiles first
    const int bh = blockIdx.y;
    const int q0 = qt * BQ;

    const float* Qb = Qg + (size_t)bh * T_SEQ * D_HEAD;
    const float* Kb = Kg + (size_t)bh * T_SEQ * D_HEAD;
    const float* Vb = Vg + (size_t)bh * T_SEQ * D_HEAD;
    float*       Ob = Og + (size_t)bh * T_SEQ * D_HEAD;

    const int qw      = q0 + 32 * w;     // wave's first q row
    const int q_lane  = qw + r;          // this lane's q column (S^T layout)
    const int qw_last = qw + 31;

    // ---- Q fragments (B-operand: B[k=d][n=q]), pre-scaled by 1/sqrt(D)*log2(e)
    const float qscale = 0.08838834764831845f * 1.4426950408889634f;
    bf16x8 qf[8];
#pragma unroll
    for (int c = 0; c < 8; ++c) {
        const float* src = Qb + (size_t)q_lane * D_HEAD + c * 16 + h * 8;
        float4 f0 = *(const float4*)(src);
        float4 f1 = *(const float4*)(src + 4);
        u16x8 u;
        u[0] = f2bf(f0.x * qscale); u[1] = f2bf(f0.y * qscale);
        u[2] = f2bf(f0.z * qscale); u[3] = f2bf(f0.w * qscale);
        u[4] = f2bf(f1.x * qscale); u[5] = f2bf(f1.y * qscale);
        u[6] = f2bf(f1.z * qscale); u[7] = f2bf(f1.w * qscale);
        qf[c] = __builtin_bit_cast(bf16x8, u);
    }

    f32x16 o[4];                      // O^T accum, 4 d-blocks of 32
#pragma unroll
    for (int mt = 0; mt < 4; ++mt) o[mt] = (f32x16)0.0f;
    float m_run = -1e30f, l_run = 0.0f;

    unsigned short* Pw = &Pq_lds[w * 32 * PSTR];

    const int ntiles = 2 * qt + 2;
    for (int kt = 0; kt < ntiles; ++kt) {
        const int kbase = kt * BK;
        __syncthreads();   // previous tile's LDS reads done before restage

        // ---- stage K tile: K_lds[row][d], coalesced float4 reads
        {
            const int row = tid >> 5;            // 0..7
            const int d0  = (tid & 31) * 4;
#pragma unroll
            for (int p = 0; p < 8; ++p) {
                const int rr = p * 8 + row;
                float4 kf = *(const float4*)(Kb + (size_t)(kbase + rr) * D_HEAD + d0);
                u16x4 u;
                u[0] = f2bf(kf.x); u[1] = f2bf(kf.y); u[2] = f2bf(kf.z); u[3] = f2bf(kf.w);
                *(u16x4*)&K_lds[rr * KSTR + d0] = u;
            }
        }
        // ---- stage V tile transposed: Vt_lds[d][kv], coalesced scalar reads
        {
            const int d  = tid & 127;
            const int hh = tid >> 7;             // 0,1
#pragma unroll
            for (int p = 0; p < 8; ++p) {
                const int kv0 = p * 8 + hh * 4;
                const float* vs = Vb + (size_t)(kbase + kv0) * D_HEAD + d;
                u16x4 u;
                u[0] = f2bf(vs[0]);
                u[1] = f2bf(vs[D_HEAD]);
                u[2] = f2bf(vs[2 * D_HEAD]);
                u[3] = f2bf(vs[3 * D_HEAD]);
                *(u16x4*)&Vt_lds[d * VSTR + kv0] = u;
            }
        }
        __syncthreads();

        if (kbase > qw_last) continue;   // wave-uniform skip; barriers stay aligned

        // ---- S^T = K * Q^T : two 32-kv m-tiles
        f32x16 s[2];
        s[0] = (f32x16)0.0f; s[1] = (f32x16)0.0f;
#pragma unroll
        for (int t = 0; t < 2; ++t) {
#pragma unroll
            for (int c = 0; c < 8; ++c) {
                u16x8 raw = *(const u16x8*)&K_lds[(t * 32 + r) * KSTR + c * 16 + h * 8];
                bf16x8 a = __builtin_bit_cast(bf16x8, raw);
                s[t] = __builtin_amdgcn_mfma_f32_32x32x16_bf16(a, qf[c], s[t], 0, 0, 0);
            }
        }

        // ---- causal mask: needed iff tile contains kv beyond the wave's FIRST q
        //      (BUG FIX from R1: was `> qw_last`, which skipped masking for waves
        //       whose q-range ends exactly at the tile end — leaked future tokens)
        if (kbase + BK - 1 > qw) {
#pragma unroll
            for (int t = 0; t < 2; ++t)
#pragma unroll
                for (int g = 0; g < 16; ++g) {
                    int kv = kbase + t * 32 + (g & 3) + 8 * (g >> 2) + 4 * h;
                    if (kv > q_lane) s[t][g] = -1e30f;
                }
        }

        // ---- online softmax (per q = lane&31; combine the two half-waves)
        float mloc = -1e30f;
#pragma unroll
        for (int t = 0; t < 2; ++t)
#pragma unroll
            for (int g = 0; g < 16; ++g) mloc = fmaxf(mloc, s[t][g]);
        mloc = fmaxf(mloc, __shfl_xor(mloc, 32, 64));
        const float m_new = fmaxf(m_run, mloc);
        const float alpha = __builtin_amdgcn_exp2f(m_run - m_new);
        float rsum = 0.0f;
#pragma unroll
        for (int t = 0; t < 2; ++t)
#pragma unroll
            for (int g = 0; g < 16; ++g) {
                float p = __builtin_amdgcn_exp2f(s[t][g] - m_new);
                s[t][g] = p;
                rsum += p;
            }
        rsum += __shfl_xor(rsum, 32, 64);
        l_run = l_run * alpha + rsum;
        m_run = m_new;
#pragma unroll
        for (int mt = 0; mt < 4; ++mt)
#pragma unroll
            for (int g = 0; g < 16; ++g) o[mt][g] *= alpha;

        // ---- P to LDS: Pq[q=r][kv], vectorized b64 writes (C-layout rows are
        //      4 consecutive kv for fixed reg-group)
#pragma unroll
        for (int t = 0; t < 2; ++t)
#pragma unroll
            for (int g4 = 0; g4 < 4; ++g4) {
                u16x4 u;
                u[0] = f2bf(s[t][g4 * 4 + 0]);
                u[1] = f2bf(s[t][g4 * 4 + 1]);
                u[2] = f2bf(s[t][g4 * 4 + 2]);
                u[3] = f2bf(s[t][g4 * 4 + 3]);
                *(u16x4*)&Pw[r * PSTR + t * 32 + g4 * 8 + h * 4] = u;
            }

        // ---- P^T B-fragments (b128 reads), then O^T += V^T * P^T
        bf16x8 pf[4];
#pragma unroll
        for (int c = 0; c < 4; ++c) {
            u16x8 raw = *(const u16x8*)&Pw[r * PSTR + c * 16 + h * 8];
            pf[c] = __builtin_bit_cast(bf16x8, raw);
        }
#pragma unroll
        for (int mt = 0; mt < 4; ++mt) {
#pragma unroll
            for (int c = 0; c < 4; ++c) {
                u16x8 raw = *(const u16x8*)&Vt_lds[(mt * 32 + r) * VSTR + c * 16 + h * 8];
                bf16x8 a = __builtin_bit_cast(bf16x8, raw);
                o[mt] = __builtin_amdgcn_mfma_f32_32x32x16_bf16(a, pf[c], o[mt], 0, 0, 0);
            }
        }
    }

    // ---- epilogue: O[q][d] = O^T / l  (float4 stores, lane's q row fixed)
    const float inv = 1.0f / l_run;
#pragma unroll
    for (int mt = 0; mt < 4; ++mt)
#pragma unroll
        for (int g4 = 0; g4 < 4; ++g4) {
            float4 vv;
            vv.x = o[mt][g4 * 4 + 0] * inv;
            vv.y = o[mt][g4 * 4 + 1] * inv;
            vv.z = o[mt][g4 * 4 + 2] * inv;
            vv.w = o[mt][g4 * 4 + 3] * inv;
            const int dd = mt * 32 + g4 * 8 + h * 4;
            *(float4*)(Ob + (size_t)q_lane * D_HEAD + dd) = vv;
        }
}

extern "C" void kernel_launch(void* const* d_in, const int* in_sizes, int n_in,
                              void* d_out, int out_size, void* d_ws, size_t ws_size,
                              hipStream_t stream) {
    const float* Q = (const float*)d_in[0];
    const float* K = (const float*)d_in[1];
    const float* V = (const float*)d_in[2];
    float* O = (float*)d_out;
    const int BH = in_sizes[0] / (T_SEQ * D_HEAD);   // 32
    dim3 grid(T_SEQ / BQ, BH, 1);
    fa_fwd<<<grid, 256, 0, stream>>>(Q, K, V, O);
}